// Round 9
// baseline (16196.477 us; speedup 1.0000x reference)
//
#include <hip/hip_runtime.h>
#include <math.h>

// ---------------- problem constants ----------------
#define EMBED 1024
#define SLEN  2048
#define BATCH 2
#define HEADS 16
#define HD    64
#define FFN_D 4096
#define MROWS (BATCH*SLEN)   // 4096

__device__ inline float b2f(short s) {
  union { unsigned u; float f; } c; c.u = ((unsigned)(unsigned short)s) << 16; return c.f;
}
__device__ inline short f2b(float f) {
  union { float f; unsigned u; } c; c.f = f;
  unsigned r = (c.u + 0x7FFFu + ((c.u >> 16) & 1u)) >> 16;   // RNE
  return (short)r;
}

// ---------------- layernorm: one block per row (1024 cols) ----------------
// exactly one of inF (fp32) / inB (bf16) is non-null
__global__ __launch_bounds__(256) void ln_kernel(const float* __restrict__ inF,
                                                 const short* __restrict__ inB,
                                                 const float* __restrict__ gw,
                                                 const float* __restrict__ bw,
                                                 short* __restrict__ out) {
  const int row = blockIdx.x, tid = threadIdx.x;
  const int w = tid >> 6;
  const size_t base = (size_t)row * EMBED;
  float x[4];
#pragma unroll
  for (int i = 0; i < 4; ++i) {
    int c = tid + i * 256;
    x[i] = inF ? inF[base + c] : b2f(inB[base + c]);
  }
  float s = x[0] + x[1] + x[2] + x[3];
  float ss = x[0]*x[0] + x[1]*x[1] + x[2]*x[2] + x[3]*x[3];
#pragma unroll
  for (int off = 32; off >= 1; off >>= 1) { s += __shfl_xor(s, off); ss += __shfl_xor(ss, off); }
  __shared__ float red[8];
  if ((tid & 63) == 0) { red[w*2] = s; red[w*2+1] = ss; }
  __syncthreads();
  s  = red[0] + red[2] + red[4] + red[6];
  ss = red[1] + red[3] + red[5] + red[7];
  const float mu = s * (1.0f/EMBED);
  const float var = ss * (1.0f/EMBED) - mu*mu;
  const float rstd = rsqrtf(var + 1e-5f);
#pragma unroll
  for (int i = 0; i < 4; ++i) {
    int c = tid + i * 256;
    out[base + c] = f2b((x[i]-mu)*rstd*gw[c] + bw[c]);
  }
}

// ---------------- RoPE in-place on Q,K (pair d / d+32 per thread) ----------------
__global__ __launch_bounds__(256) void rope_kernel(short* __restrict__ Qb, short* __restrict__ Kb,
                                                   const float* __restrict__ cosb,
                                                   const float* __restrict__ sinb) {
  const int idx = blockIdx.x * 256 + threadIdx.x;      // < 2*2048*16*32 = 2M
  const int d = idx & 31;
  const int h = (idx >> 5) & 15;
  const int s = (idx >> 9) & 2047;
  const int b = idx >> 20;
  const size_t base = ((size_t)(b*SLEN + s))*EMBED + h*HD;
  const float c0 = cosb[s*HD + d],      s0 = sinb[s*HD + d];
  const float c1 = cosb[s*HD + 32 + d], s1 = sinb[s*HD + 32 + d];
  float q0 = b2f(Qb[base + d]), q1 = b2f(Qb[base + 32 + d]);
  Qb[base + d]      = f2b(q0*c0 - q1*s0);
  Qb[base + 32 + d] = f2b(q1*c1 + q0*s1);
  float k0 = b2f(Kb[base + d]), k1 = b2f(Kb[base + 32 + d]);
  Kb[base + d]      = f2b(k0*c0 - k1*s0);
  Kb[base + 32 + d] = f2b(k1*c1 + k0*s1);
}

// ---------------- naive GEMM: C[row,col] = sum_k A(bf16)[row,k] * W(fp32,(K,N))[k,col] ----
// exactly one of outF/outB non-null; resid: residF (fp32) or residB (bf16) or none
__global__ __launch_bounds__(256) void gemm_naive(const short* __restrict__ A,
                                                  const float* __restrict__ W,
                                                  const float* __restrict__ bias,
                                                  float* __restrict__ outF,
                                                  short* __restrict__ outB,
                                                  const float* __restrict__ residF,
                                                  const short* __restrict__ residB,
                                                  int N, int K, int gelu) {
  const int row = blockIdx.y;
  const int col = blockIdx.x * 256 + threadIdx.x;
  const short* arow = A + (size_t)row * K;
  float acc = 0.f;
  for (int k = 0; k < K; k += 4) {
    acc += b2f(arow[k+0]) * W[(size_t)(k+0)*N + col];
    acc += b2f(arow[k+1]) * W[(size_t)(k+1)*N + col];
    acc += b2f(arow[k+2]) * W[(size_t)(k+2)*N + col];
    acc += b2f(arow[k+3]) * W[(size_t)(k+3)*N + col];
  }
  float v = acc + (bias ? bias[col] : 0.f);
  if (gelu) v = 0.5f*v*(1.f + erff(v*0.70710678f));
  if (residF) v += residF[(size_t)row*N + col];
  if (residB) v += b2f(residB[(size_t)row*N + col]);
  if (outF) outF[(size_t)row*N + col] = v;
  if (outB) outB[(size_t)row*N + col] = f2b(v);
}

// ---------------- naive attention: one wave per q-row, lane = d ----------------
__global__ __launch_bounds__(256) void attn_naive(const short* __restrict__ Qb,
                                                  const short* __restrict__ Kb,
                                                  const short* __restrict__ Vb,
                                                  short* __restrict__ AOb) {
  const int tid = threadIdx.x;
  const int rowid = blockIdx.x*4 + (tid >> 6);   // < 65536 = B*H*S
  const int d = tid & 63;
  const int q = rowid & 2047;
  const int h = (rowid >> 11) & 15;
  const int b = rowid >> 15;
  const size_t base = ((size_t)(b*SLEN))*EMBED + h*HD;
  const float qv = b2f(Qb[base + (size_t)q*EMBED + d]);
  float m = -1e30f, l = 0.f, o = 0.f;
  for (int key = 0; key <= q; ++key) {
    const size_t krow = base + (size_t)key*EMBED + d;
    const float kd = b2f(Kb[krow]);
    const float vd = b2f(Vb[krow]);
    float s = qv * kd;
#pragma unroll
    for (int off = 32; off >= 1; off >>= 1) s += __shfl_xor(s, off);
    s *= 0.125f;
    const float mnew = fmaxf(m, s);
    const float alpha = __expf(m - mnew);
    const float p = __expf(s - mnew);
    l = l*alpha + p;
    o = o*alpha + p*vd;
    m = mnew;
  }
  AOb[base + (size_t)q*EMBED + d] = f2b(o / l);
}

// ---------------- launcher ----------------
extern "C" void kernel_launch(void* const* d_in, const int* in_sizes, int n_in,
                              void* d_out, int out_size, void* d_ws, size_t ws_size,
                              hipStream_t stream) {
  // inputs: fp32, dict order (confirmed: round-8 identity mapping reproduced round 6 bit-exactly)
  const float* x    = (const float*)d_in[0];
  const float* cosb = (const float*)d_in[1];
  const float* sinb = (const float*)d_in[2];
  const float* Wq = (const float*)d_in[3];  const float* bq  = (const float*)d_in[4];
  const float* Wk = (const float*)d_in[5];  const float* bk  = (const float*)d_in[6];
  const float* Wv = (const float*)d_in[7];  const float* bv  = (const float*)d_in[8];
  const float* Wo = (const float*)d_in[9];  const float* bo  = (const float*)d_in[10];
  const float* W1 = (const float*)d_in[11]; const float* b1  = (const float*)d_in[12];
  const float* W2 = (const float*)d_in[13]; const float* b2  = (const float*)d_in[14];
  const float* g1 = (const float*)d_in[15]; const float* be1 = (const float*)d_in[16];
  const float* g2 = (const float*)d_in[17]; const float* be2 = (const float*)d_in[18];
  float* out = (float*)d_out;   // reference output dtype = float32

  // workspace, peak 48MB, all internal buffers bf16
  char* ws = (char*)d_ws;
  const size_t MB = 1ull << 20;
  short* n1b = (short*)(ws + 0*MB);    // [0,8)   -> X1b later
  short* Qb  = (short*)(ws + 8*MB);    // [8,16)  -> n2b later
  short* Kb  = (short*)(ws + 16*MB);   // [16,24) -> Hb[0:8)
  short* Vb  = (short*)(ws + 24*MB);   // [24,32) -> Hb[8:16)
  short* AOb = (short*)(ws + 32*MB);   // [32,40) -> Hb[16:24)
  short* X1b = (short*)(ws + 0*MB);    // reuse n1b (dead after QKV)
  short* n2b = (short*)(ws + 8*MB);    // reuse Qb (dead after attn)
  short* Hb  = (short*)(ws + 16*MB);   // [16,48) reuse Kb,Vb,AOb + fresh 8MB

  // LN1 (fp32 in)
  ln_kernel<<<MROWS, 256, 0, stream>>>(x, nullptr, g1, be1, n1b);

  // QKV projections
  gemm_naive<<<dim3(4, MROWS), 256, 0, stream>>>(n1b, Wq, bq, nullptr, Qb, nullptr, nullptr, 1024, 1024, 0);
  gemm_naive<<<dim3(4, MROWS), 256, 0, stream>>>(n1b, Wk, bk, nullptr, Kb, nullptr, nullptr, 1024, 1024, 0);
  gemm_naive<<<dim3(4, MROWS), 256, 0, stream>>>(n1b, Wv, bv, nullptr, Vb, nullptr, nullptr, 1024, 1024, 0);

  // RoPE on Q,K
  rope_kernel<<<8192, 256, 0, stream>>>(Qb, Kb, cosb, sinb);

  // attention (naive)
  attn_naive<<<16384, 256, 0, stream>>>(Qb, Kb, Vb, AOb);

  // O projection + residual(x fp32) -> X1b (bf16)
  gemm_naive<<<dim3(4, MROWS), 256, 0, stream>>>(AOb, Wo, bo, nullptr, X1b, x, nullptr, 1024, 1024, 0);

  // LN2 (bf16 in)
  ln_kernel<<<MROWS, 256, 0, stream>>>(nullptr, X1b, g2, be2, n2b);

  // FFN1 + exact GELU -> Hb (bf16)
  gemm_naive<<<dim3(16, MROWS), 256, 0, stream>>>(n2b, W1, b1, nullptr, Hb, nullptr, nullptr, 4096, 1024, 1);

  // FFN2 + residual(X1b) -> d_out (fp32!)
  gemm_naive<<<dim3(4, MROWS), 256, 0, stream>>>(Hb, W2, b2, out, nullptr, nullptr, X1b, 1024, 4096, 0);
}

// Round 10
// 696.281 us; speedup vs baseline: 23.2614x; 23.2614x over previous
//
#include <hip/hip_runtime.h>
#include <math.h>

// ---------------- problem constants ----------------
#define EMBED 1024
#define SLEN  2048
#define BATCH 2
#define HEADS 16
#define HD    64
#define FFN_D 4096
#define MROWS (BATCH*SLEN)   // 4096

typedef short bh8  __attribute__((ext_vector_type(8)));   // 8 bf16 in 4 VGPRs
typedef float f32x4 __attribute__((ext_vector_type(4)));

#define MFMA16(a,b,c) __builtin_amdgcn_mfma_f32_16x16x32_bf16((a),(b),(c),0,0,0)

__device__ inline float b2f(short s) {
  union { unsigned u; float f; } c; c.u = ((unsigned)(unsigned short)s) << 16; return c.f;
}
__device__ inline short f2b(float f) {
  union { float f; unsigned u; } c; c.f = f;
  unsigned r = (c.u + 0x7FFFu + ((c.u >> 16) & 1u)) >> 16;   // RNE
  return (short)r;
}

// ---------------- weight transpose: fp32 (K,N) -> bf16 (N,K) ----------------
__global__ __launch_bounds__(256) void transpose_w(const float* __restrict__ in,
                                                   short* __restrict__ out,
                                                   int K, int N) {
  __shared__ short sm[64][65];
  const int tid = threadIdx.x;
  const int k0 = blockIdx.y * 64, n0 = blockIdx.x * 64;
#pragma unroll
  for (int it = 0; it < 16; ++it) {
    int idx = it * 256 + tid;
    int r = idx >> 6, c = idx & 63;
    sm[r][c] = f2b(in[(size_t)(k0 + r) * N + n0 + c]);
  }
  __syncthreads();
#pragma unroll
  for (int it = 0; it < 16; ++it) {
    int idx = it * 256 + tid;
    int r = idx >> 6, c = idx & 63;
    out[(size_t)(n0 + r) * K + k0 + c] = sm[c][r];
  }
}

// ---------------- layernorm: one block per row (1024 cols) ----------------
__global__ __launch_bounds__(256) void ln_kernel(const float* __restrict__ inF,
                                                 const short* __restrict__ inB,
                                                 const float* __restrict__ gw,
                                                 const float* __restrict__ bw,
                                                 short* __restrict__ out) {
  const int row = blockIdx.x, tid = threadIdx.x;
  const int w = tid >> 6;
  const size_t base = (size_t)row * EMBED;
  float x[4];
#pragma unroll
  for (int i = 0; i < 4; ++i) {
    int c = tid + i * 256;
    x[i] = inF ? inF[base + c] : b2f(inB[base + c]);
  }
  float s = x[0] + x[1] + x[2] + x[3];
  float ss = x[0]*x[0] + x[1]*x[1] + x[2]*x[2] + x[3]*x[3];
#pragma unroll
  for (int off = 32; off >= 1; off >>= 1) { s += __shfl_xor(s, off); ss += __shfl_xor(ss, off); }
  __shared__ float red[8];
  if ((tid & 63) == 0) { red[w*2] = s; red[w*2+1] = ss; }
  __syncthreads();
  s  = red[0] + red[2] + red[4] + red[6];
  ss = red[1] + red[3] + red[5] + red[7];
  const float mu = s * (1.0f/EMBED);
  const float var = ss * (1.0f/EMBED) - mu*mu;
  const float rstd = rsqrtf(var + 1e-5f);
#pragma unroll
  for (int i = 0; i < 4; ++i) {
    int c = tid + i * 256;
    out[base + c] = f2b((x[i]-mu)*rstd*gw[c] + bw[c]);
  }
}

// ---------------- RoPE in-place on Q,K (pair d / d+32 per thread) ----------------
__global__ __launch_bounds__(256) void rope_kernel(short* __restrict__ Qb, short* __restrict__ Kb,
                                                   const float* __restrict__ cosb,
                                                   const float* __restrict__ sinb) {
  const int idx = blockIdx.x * 256 + threadIdx.x;      // < 2M
  const int d = idx & 31;
  const int h = (idx >> 5) & 15;
  const int s = (idx >> 9) & 2047;
  const int b = idx >> 20;
  const size_t base = ((size_t)(b*SLEN + s))*EMBED + h*HD;
  const float c0 = cosb[s*HD + d],      s0 = sinb[s*HD + d];
  const float c1 = cosb[s*HD + 32 + d], s1 = sinb[s*HD + 32 + d];
  float q0 = b2f(Qb[base + d]), q1 = b2f(Qb[base + 32 + d]);
  Qb[base + d]      = f2b(q0*c0 - q1*s0);
  Qb[base + 32 + d] = f2b(q1*c1 + q0*s1);
  float k0 = b2f(Kb[base + d]), k1 = b2f(Kb[base + 32 + d]);
  Kb[base + d]      = f2b(k0*c0 - k1*s0);
  Kb[base + 32 + d] = f2b(k1*c1 + k0*s1);
}

// ---------------- MFMA GEMM: C[M,N] = A[M,K](bf16) x Bt[N,K](bf16) + epilogue ----
// 128x128 tile, BK=32, 4 waves x (4x4) 16x16x32 MFMA. m93 pattern.
__global__ __launch_bounds__(256) void gemm_bt(const short* __restrict__ A,
                                               const short* __restrict__ Bt,
                                               const float* __restrict__ bias,
                                               float* __restrict__ outF,
                                               short* __restrict__ outB,
                                               const float* __restrict__ residF,
                                               const short* __restrict__ residB,
                                               int N, int K, int gelu) {
  __shared__ short As[128*32];
  __shared__ short Bs[128*32];
  const int tid = threadIdx.x;
  const int w = tid >> 6, L = tid & 63;
  const int quad = L >> 4, l16 = L & 15;
  const int bm = blockIdx.y * 128, bn = blockIdx.x * 128;
  const int wm = (w >> 1) * 64, wn = (w & 1) * 64;

  f32x4 acc[4][4];
#pragma unroll
  for (int i = 0; i < 4; ++i)
#pragma unroll
    for (int j = 0; j < 4; ++j) acc[i][j] = (f32x4){0.f,0.f,0.f,0.f};

  // chunk c: global row (c>>2), k-span (c&3)*8; lands at LDS shorts c*8
  const int c0 = tid, c1 = tid + 256;
  const short* a0p = A  + (size_t)(bm + (c0 >> 2))*K + (c0 & 3)*8;
  const short* a1p = A  + (size_t)(bm + (c1 >> 2))*K + (c1 & 3)*8;
  const short* b0p = Bt + (size_t)(bn + (c0 >> 2))*K + (c0 & 3)*8;
  const short* b1p = Bt + (size_t)(bn + (c1 >> 2))*K + (c1 & 3)*8;

  for (int k0 = 0; k0 < K; k0 += 32) {
    bh8 va0 = *(const bh8*)(a0p + k0);
    bh8 va1 = *(const bh8*)(a1p + k0);
    bh8 vb0 = *(const bh8*)(b0p + k0);
    bh8 vb1 = *(const bh8*)(b1p + k0);
    *(bh8*)(As + c0*8) = va0;
    *(bh8*)(As + c1*8) = va1;
    *(bh8*)(Bs + c0*8) = vb0;
    *(bh8*)(Bs + c1*8) = vb1;
    __syncthreads();
    bh8 af[4], bf[4];
#pragma unroll
    for (int mi = 0; mi < 4; ++mi)
      af[mi] = *(const bh8*)(As + (wm + mi*16 + l16)*32 + quad*8);
#pragma unroll
    for (int ni = 0; ni < 4; ++ni)
      bf[ni] = *(const bh8*)(Bs + (wn + ni*16 + l16)*32 + quad*8);
#pragma unroll
    for (int mi = 0; mi < 4; ++mi)
#pragma unroll
      for (int ni = 0; ni < 4; ++ni)
        acc[mi][ni] = MFMA16(af[mi], bf[ni], acc[mi][ni]);
    __syncthreads();
  }

  // epilogue: C/D layout col=l16, row=quad*4+r (m89/m91)
#pragma unroll
  for (int mi = 0; mi < 4; ++mi) {
#pragma unroll
    for (int ni = 0; ni < 4; ++ni) {
      const int col = bn + wn + ni*16 + l16;
      const float bv = bias ? bias[col] : 0.f;
#pragma unroll
      for (int r = 0; r < 4; ++r) {
        const int gr = bm + wm + mi*16 + quad*4 + r;
        float v = acc[mi][ni][r] + bv;
        if (gelu) v = 0.5f*v*(1.f + erff(v*0.70710678f));
        if (residF) v += residF[(size_t)gr*N + col];
        if (residB) v += b2f(residB[(size_t)gr*N + col]);
        if (outF) outF[(size_t)gr*N + col] = v;
        if (outB) outB[(size_t)gr*N + col] = f2b(v);
      }
    }
  }
}

// ---------------- MFMA flash attention: block = (64-q-tile, b*h), 4 waves ----------
__global__ __launch_bounds__(256) void attn_kernel(const short* __restrict__ Qb,
                                                   const short* __restrict__ Kb,
                                                   const short* __restrict__ Vb,
                                                   short* __restrict__ AOb) {
  __shared__ short Klds[32*72];     // [key][d], stride 72
  __shared__ short Vt[64*40];       // [d][key], stride 40
  __shared__ short Plds[4*16*40];   // per-wave P 16x32, stride 40
  const int tid = threadIdx.x;
  const int w = tid >> 6, L = tid & 63, quad = L >> 4, l16 = L & 15;
  const int qt = blockIdx.x, bh = blockIdx.y;
  const int b = bh >> 4, h = bh & 15;
  const int qbase = qt*64 + w*16;

  // Q fragments, A-layout: m=l16, k(d)=quad*8+j (+32 chunk 1)  [m120]
  const size_t qrow = ((size_t)(b*SLEN + qbase + l16))*EMBED + h*HD;
  const bh8 aq0 = *(const bh8*)(Qb + qrow + quad*8);
  const bh8 aq1 = *(const bh8*)(Qb + qrow + 32 + quad*8);

  f32x4 o[4];
#pragma unroll
  for (int i = 0; i < 4; ++i) o[i] = (f32x4){0.f,0.f,0.f,0.f};
  float m_r[4] = {-1e30f,-1e30f,-1e30f,-1e30f};
  float l_r[4] = {0.f,0.f,0.f,0.f};
  const float scale = 0.125f;                 // 1/sqrt(64)
  const size_t kvbase = ((size_t)(b*SLEN))*EMBED + h*HD;
  const int ktmax = 2*qt + 1;

  for (int kt = 0; kt <= ktmax; ++kt) {
    const int kbase = kt*32;
    __syncthreads();                           // prev-iter LDS readers done
#pragma unroll
    for (int it = 0; it < 8; ++it) {
      int idx = it*256 + tid;
      int key = idx >> 6, d = idx & 63;
      size_t g = kvbase + (size_t)(kbase + key)*EMBED + d;
      Klds[key*72 + d] = Kb[g];
      Vt[d*40 + key]   = Vb[g];
    }
    __syncthreads();

    // S = Q K^T  (B-frag: n=key=l16(+16), k=d=quad*8+j(+32))
    f32x4 s0 = (f32x4){0.f,0.f,0.f,0.f}, s1 = s0;
    {
      const short* kp0 = Klds + l16*72 + quad*8;
      s0 = MFMA16(aq0, *(const bh8*)kp0,        s0);
      s0 = MFMA16(aq1, *(const bh8*)(kp0 + 32), s0);
      const short* kp1 = Klds + (16 + l16)*72 + quad*8;
      s1 = MFMA16(aq0, *(const bh8*)kp1,        s1);
      s1 = MFMA16(aq1, *(const bh8*)(kp1 + 32), s1);
    }

    // online softmax per row (row = qbase + quad*4 + r; quad's 16 lanes hold 32 keys)
#pragma unroll
    for (int r = 0; r < 4; ++r) {
      const int q = qbase + quad*4 + r;
      float v0 = s0[r]*scale; if (kbase + l16 > q)      v0 = -1e30f;
      float v1 = s1[r]*scale; if (kbase + 16 + l16 > q) v1 = -1e30f;
      float mx = fmaxf(v0, v1);
#pragma unroll
      for (int off = 8; off >= 1; off >>= 1) mx = fmaxf(mx, __shfl_xor(mx, off));
      const float mnew = fmaxf(m_r[r], mx);
      const float alpha = __expf(m_r[r] - mnew);
      const float p0 = __expf(v0 - mnew), p1 = __expf(v1 - mnew);
      float rs = p0 + p1;
#pragma unroll
      for (int off = 8; off >= 1; off >>= 1) rs += __shfl_xor(rs, off);
      l_r[r] = l_r[r]*alpha + rs;
      m_r[r] = mnew;
#pragma unroll
      for (int dt = 0; dt < 4; ++dt) o[dt][r] *= alpha;
      Plds[w*640 + (quad*4 + r)*40 + l16]      = f2b(p0);
      Plds[w*640 + (quad*4 + r)*40 + 16 + l16] = f2b(p1);
    }
    __syncthreads();

    // P (A-layout) x V -> O
    const bh8 pf = *(const bh8*)(Plds + w*640 + l16*40 + quad*8);
#pragma unroll
    for (int dt = 0; dt < 4; ++dt) {
      const bh8 bv = *(const bh8*)(Vt + (dt*16 + l16)*40 + quad*8);
      o[dt] = MFMA16(pf, bv, o[dt]);
    }
  }

#pragma unroll
  for (int r = 0; r < 4; ++r) {
    const float inv = 1.0f / l_r[r];
    const size_t orow = ((size_t)(b*SLEN + qbase + quad*4 + r))*EMBED + h*HD;
#pragma unroll
    for (int dt = 0; dt < 4; ++dt)
      AOb[orow + dt*16 + l16] = f2b(o[dt][r]*inv);
  }
}

// ---------------- launcher ----------------
extern "C" void kernel_launch(void* const* d_in, const int* in_sizes, int n_in,
                              void* d_out, int out_size, void* d_ws, size_t ws_size,
                              hipStream_t stream) {
  const float* x    = (const float*)d_in[0];
  const float* cosb = (const float*)d_in[1];
  const float* sinb = (const float*)d_in[2];
  const float* Wq = (const float*)d_in[3];  const float* bq  = (const float*)d_in[4];
  const float* Wk = (const float*)d_in[5];  const float* bk  = (const float*)d_in[6];
  const float* Wv = (const float*)d_in[7];  const float* bv  = (const float*)d_in[8];
  const float* Wo = (const float*)d_in[9];  const float* bo  = (const float*)d_in[10];
  const float* W1 = (const float*)d_in[11]; const float* b1  = (const float*)d_in[12];
  const float* W2 = (const float*)d_in[13]; const float* b2  = (const float*)d_in[14];
  const float* g1 = (const float*)d_in[15]; const float* be1 = (const float*)d_in[16];
  const float* g2 = (const float*)d_in[17]; const float* be2 = (const float*)d_in[18];
  float* out = (float*)d_out;   // fp32 output (confirmed round 9)

  // workspace, peak 64MB
  char* ws = (char*)d_ws;
  const size_t MB = 1ull << 20;
  short* wqT = (short*)(ws + 0*MB);    // [0,2)
  short* wkT = (short*)(ws + 2*MB);    // [2,4)
  short* wvT = (short*)(ws + 4*MB);    // [4,6)
  short* woT = (short*)(ws + 6*MB);    // [6,8)
  short* w2T = (short*)(ws + 0*MB);    // [0,8) reuse after O-proj
  short* w1T = (short*)(ws + 8*MB);    // [8,16)
  short* n1b = (short*)(ws + 16*MB);   // [16,24) -> X1b
  short* Qb  = (short*)(ws + 24*MB);   // [24,32) -> n2b
  short* Kb  = (short*)(ws + 32*MB);   // [32,40) -> Hb[0:8)
  short* Vb  = (short*)(ws + 40*MB);   // [40,48) -> Hb[8:16)
  short* AOb = (short*)(ws + 48*MB);   // [48,56) -> Hb[16:24)
  short* X1b = (short*)(ws + 16*MB);
  short* n2b = (short*)(ws + 24*MB);
  short* Hb  = (short*)(ws + 32*MB);   // [32,64)

  // weight prep (W2 transposed later, into dead Wq..Wo slots)
  transpose_w<<<dim3(16,16), 256, 0, stream>>>(Wq, wqT, 1024, 1024);
  transpose_w<<<dim3(16,16), 256, 0, stream>>>(Wk, wkT, 1024, 1024);
  transpose_w<<<dim3(16,16), 256, 0, stream>>>(Wv, wvT, 1024, 1024);
  transpose_w<<<dim3(16,16), 256, 0, stream>>>(Wo, woT, 1024, 1024);
  transpose_w<<<dim3(64,16), 256, 0, stream>>>(W1, w1T, 1024, 4096);

  // LN1
  ln_kernel<<<MROWS, 256, 0, stream>>>(x, nullptr, g1, be1, n1b);

  // QKV projections (MFMA)
  gemm_bt<<<dim3(8,32), 256, 0, stream>>>(n1b, wqT, bq, nullptr, Qb, nullptr, nullptr, 1024, 1024, 0);
  gemm_bt<<<dim3(8,32), 256, 0, stream>>>(n1b, wkT, bk, nullptr, Kb, nullptr, nullptr, 1024, 1024, 0);
  gemm_bt<<<dim3(8,32), 256, 0, stream>>>(n1b, wvT, bv, nullptr, Vb, nullptr, nullptr, 1024, 1024, 0);

  // RoPE
  rope_kernel<<<8192, 256, 0, stream>>>(Qb, Kb, cosb, sinb);

  // flash attention (MFMA)
  attn_kernel<<<dim3(32,32), 256, 0, stream>>>(Qb, Kb, Vb, AOb);

  // O projection + residual(x fp32) -> X1b
  gemm_bt<<<dim3(8,32), 256, 0, stream>>>(AOb, woT, bo, nullptr, X1b, x, nullptr, 1024, 1024, 0);

  // W2 transpose into freed region
  transpose_w<<<dim3(16,64), 256, 0, stream>>>(W2, w2T, 4096, 1024);

  // LN2
  ln_kernel<<<MROWS, 256, 0, stream>>>(nullptr, X1b, g2, be2, n2b);

  // FFN1 + GELU
  gemm_bt<<<dim3(32,32), 256, 0, stream>>>(n2b, w1T, b1, nullptr, Hb, nullptr, nullptr, 4096, 1024, 1);

  // FFN2 + residual(X1b) -> out (fp32)
  gemm_bt<<<dim3(8,32), 256, 0, stream>>>(Hb, w2T, b2, out, nullptr, nullptr, X1b, 1024, 4096, 0);
}

// Round 11
// 505.950 us; speedup vs baseline: 32.0120x; 1.3762x over previous
//
#include <hip/hip_runtime.h>
#include <math.h>

// ---------------- problem constants ----------------
#define EMBED 1024
#define SLEN  2048
#define BATCH 2
#define HEADS 16
#define HD    64
#define FFN_D 4096
#define MROWS (BATCH*SLEN)   // 4096

typedef short bh8  __attribute__((ext_vector_type(8)));   // 8 bf16 in 4 VGPRs
typedef float f32x4 __attribute__((ext_vector_type(4)));

#define MFMA16(a,b,c) __builtin_amdgcn_mfma_f32_16x16x32_bf16((a),(b),(c),0,0,0)
#define GLDS16(g,l) __builtin_amdgcn_global_load_lds( \
    (__attribute__((address_space(1))) void*)(g), \
    (__attribute__((address_space(3))) void*)(l), 16, 0, 0)

__device__ inline float b2f(short s) {
  union { unsigned u; float f; } c; c.u = ((unsigned)(unsigned short)s) << 16; return c.f;
}
__device__ inline short f2b(float f) {
  union { float f; unsigned u; } c; c.f = f;
  unsigned r = (c.u + 0x7FFFu + ((c.u >> 16) & 1u)) >> 16;   // RNE
  return (short)r;
}

// ---------------- weight transpose: fp32 (K,N) -> bf16 (N,K) ----------------
__global__ __launch_bounds__(256) void transpose_w(const float* __restrict__ in,
                                                   short* __restrict__ out,
                                                   int K, int N) {
  __shared__ short sm[64][65];
  const int tid = threadIdx.x;
  const int k0 = blockIdx.y * 64, n0 = blockIdx.x * 64;
#pragma unroll
  for (int it = 0; it < 16; ++it) {
    int idx = it * 256 + tid;
    int r = idx >> 6, c = idx & 63;
    sm[r][c] = f2b(in[(size_t)(k0 + r) * N + n0 + c]);
  }
  __syncthreads();
#pragma unroll
  for (int it = 0; it < 16; ++it) {
    int idx = it * 256 + tid;
    int r = idx >> 6, c = idx & 63;
    out[(size_t)(n0 + r) * K + k0 + c] = sm[c][r];
  }
}

// ---------------- V transpose: Vb[(b*S+s)*E + h*64 + d] -> VT[(bh*64+d)*S + s] ----
__global__ __launch_bounds__(256) void transpose_v(const short* __restrict__ in,
                                                   short* __restrict__ out) {
  __shared__ short sm[64][65];
  const int tid = threadIdx.x;
  const int s0 = blockIdx.x * 64, bh = blockIdx.y;
  const int b = bh >> 4, h = bh & 15;
#pragma unroll
  for (int it = 0; it < 16; ++it) {
    int idx = it * 256 + tid;
    int r = idx >> 6, c = idx & 63;     // r: s offset, c: d
    sm[r][c] = in[((size_t)(b*SLEN + s0 + r))*EMBED + h*HD + c];
  }
  __syncthreads();
#pragma unroll
  for (int it = 0; it < 16; ++it) {
    int idx = it * 256 + tid;
    int r = idx >> 6, c = idx & 63;     // r: d, c: s offset
    out[((size_t)(bh*HD + r))*SLEN + s0 + c] = sm[c][r];
  }
}

// ---------------- layernorm: one block per row (1024 cols) ----------------
__global__ __launch_bounds__(256) void ln_kernel(const float* __restrict__ inF,
                                                 const short* __restrict__ inB,
                                                 const float* __restrict__ gw,
                                                 const float* __restrict__ bw,
                                                 short* __restrict__ out) {
  const int row = blockIdx.x, tid = threadIdx.x;
  const int w = tid >> 6;
  const size_t base = (size_t)row * EMBED;
  float x[4];
#pragma unroll
  for (int i = 0; i < 4; ++i) {
    int c = tid + i * 256;
    x[i] = inF ? inF[base + c] : b2f(inB[base + c]);
  }
  float s = x[0] + x[1] + x[2] + x[3];
  float ss = x[0]*x[0] + x[1]*x[1] + x[2]*x[2] + x[3]*x[3];
#pragma unroll
  for (int off = 32; off >= 1; off >>= 1) { s += __shfl_xor(s, off); ss += __shfl_xor(ss, off); }
  __shared__ float red[8];
  if ((tid & 63) == 0) { red[w*2] = s; red[w*2+1] = ss; }
  __syncthreads();
  s  = red[0] + red[2] + red[4] + red[6];
  ss = red[1] + red[3] + red[5] + red[7];
  const float mu = s * (1.0f/EMBED);
  const float var = ss * (1.0f/EMBED) - mu*mu;
  const float rstd = rsqrtf(var + 1e-5f);
#pragma unroll
  for (int i = 0; i < 4; ++i) {
    int c = tid + i * 256;
    out[base + c] = f2b((x[i]-mu)*rstd*gw[c] + bw[c]);
  }
}

// ---------------- RoPE in-place on Q,K ----------------
__global__ __launch_bounds__(256) void rope_kernel(short* __restrict__ Qb, short* __restrict__ Kb,
                                                   const float* __restrict__ cosb,
                                                   const float* __restrict__ sinb) {
  const int idx = blockIdx.x * 256 + threadIdx.x;      // < 2M
  const int d = idx & 31;
  const int h = (idx >> 5) & 15;
  const int s = (idx >> 9) & 2047;
  const int b = idx >> 20;
  const size_t base = ((size_t)(b*SLEN + s))*EMBED + h*HD;
  const float c0 = cosb[s*HD + d],      s0 = sinb[s*HD + d];
  const float c1 = cosb[s*HD + 32 + d], s1 = sinb[s*HD + 32 + d];
  float q0 = b2f(Qb[base + d]), q1 = b2f(Qb[base + 32 + d]);
  Qb[base + d]      = f2b(q0*c0 - q1*s0);
  Qb[base + 32 + d] = f2b(q1*c1 + q0*s1);
  float k0 = b2f(Kb[base + d]), k1 = b2f(Kb[base + 32 + d]);
  Kb[base + d]      = f2b(k0*c0 - k1*s0);
  Kb[base + 32 + d] = f2b(k1*c1 + k0*s1);
}

// ---------------- MFMA GEMM: 128x128 tile, BK=32, GLDS staging (m97) --------------
// qkv=1: N=3072, route cols [0,1024)->outB0(+bias0), [1024,2048)->outB1(+bias1), rest outB2(+bias2)
__global__ __launch_bounds__(256) void gemm_bt(const short* __restrict__ A,
                                               const short* __restrict__ Bt,
                                               const float* __restrict__ bias0,
                                               const float* __restrict__ bias1,
                                               const float* __restrict__ bias2,
                                               float* __restrict__ outF,
                                               short* __restrict__ outB0,
                                               short* __restrict__ outB1,
                                               short* __restrict__ outB2,
                                               const float* __restrict__ residF,
                                               const short* __restrict__ residB,
                                               int N, int K, int gelu, int qkv) {
  __shared__ short As[128*32];
  __shared__ short Bs[128*32];
  const int tid = threadIdx.x;
  const int w = tid >> 6, L = tid & 63;
  const int quad = L >> 4, l16 = L & 15;
  const int bm = blockIdx.y * 128, bn = blockIdx.x * 128;
  const int wm = (w >> 1) * 64, wn = (w & 1) * 64;

  f32x4 acc[4][4];
#pragma unroll
  for (int i = 0; i < 4; ++i)
#pragma unroll
    for (int j = 0; j < 4; ++j) acc[i][j] = (f32x4){0.f,0.f,0.f,0.f};

  // chunk c = w*64 + L (LDS dest must be wave-uniform base + lane*16B)
  const int c0 = w*64 + L, c1 = 256 + w*64 + L;
  const short* a0p = A  + (size_t)(bm + (c0 >> 2))*K + (c0 & 3)*8;
  const short* a1p = A  + (size_t)(bm + (c1 >> 2))*K + (c1 & 3)*8;
  const short* b0p = Bt + (size_t)(bn + (c0 >> 2))*K + (c0 & 3)*8;
  const short* b1p = Bt + (size_t)(bn + (c1 >> 2))*K + (c1 & 3)*8;

  for (int k0 = 0; k0 < K; k0 += 32) {
    GLDS16(a0p + k0, As + w*512);
    GLDS16(a1p + k0, As + 2048 + w*512);
    GLDS16(b0p + k0, Bs + w*512);
    GLDS16(b1p + k0, Bs + 2048 + w*512);
    __syncthreads();                    // drains vmcnt before LDS reads
    bh8 af[4], bf[4];
#pragma unroll
    for (int mi = 0; mi < 4; ++mi)
      af[mi] = *(const bh8*)(As + (wm + mi*16 + l16)*32 + quad*8);
#pragma unroll
    for (int ni = 0; ni < 4; ++ni)
      bf[ni] = *(const bh8*)(Bs + (wn + ni*16 + l16)*32 + quad*8);
#pragma unroll
    for (int mi = 0; mi < 4; ++mi)
#pragma unroll
      for (int ni = 0; ni < 4; ++ni)
        acc[mi][ni] = MFMA16(af[mi], bf[ni], acc[mi][ni]);
    __syncthreads();
  }

  // epilogue: C/D layout col=l16, row=quad*4+r
#pragma unroll
  for (int mi = 0; mi < 4; ++mi) {
#pragma unroll
    for (int ni = 0; ni < 4; ++ni) {
      const int col = bn + wn + ni*16 + l16;
      float bv; short* ob; int colw; size_t rstride;
      if (qkv) {
        const int cc = col >> 10;  // uniform per (ni): 128-tiles don't straddle 1024
        colw = col & 1023;
        bv = (cc == 0 ? bias0 : cc == 1 ? bias1 : bias2)[colw];
        ob = (cc == 0 ? outB0 : cc == 1 ? outB1 : outB2);
        rstride = 1024;
      } else {
        colw = col; bv = bias0 ? bias0[col] : 0.f; ob = outB0; rstride = N;
      }
#pragma unroll
      for (int r = 0; r < 4; ++r) {
        const int gr = bm + wm + mi*16 + quad*4 + r;
        float v = acc[mi][ni][r] + bv;
        if (gelu) v = 0.5f*v*(1.f + erff(v*0.70710678f));
        if (residF) v += residF[(size_t)gr*N + col];
        if (residB) v += b2f(residB[(size_t)gr*N + col]);
        if (outF) outF[(size_t)gr*N + col] = v;
        if (ob)   ob[(size_t)gr*rstride + colw] = f2b(v);
      }
    }
  }
}

// ---------------- MFMA flash attention v2: 64-key tiles, vectorized staging -------
// grid (bh=32, 32); qt reversed so heaviest causal blocks dispatch first.
__global__ __launch_bounds__(256) void attn_kernel(const short* __restrict__ Qb,
                                                   const short* __restrict__ Kb,
                                                   const short* __restrict__ VT,
                                                   short* __restrict__ AOb) {
  __shared__ short Klds[64*72];     // [key][d]
  __shared__ short Vlds[64*72];     // [d][key]
  __shared__ short Plds[4*16*72];   // per-wave P 16x64
  const int tid = threadIdx.x;
  const int w = tid >> 6, L = tid & 63, quad = L >> 4, l16 = L & 15;
  const int bh = blockIdx.x, qt = 31 - (int)blockIdx.y;
  const int b = bh >> 4, h = bh & 15;
  const int qbase = qt*64 + w*16;

  // Q fragments, A-layout
  const size_t qrow = ((size_t)(b*SLEN + qbase + l16))*EMBED + h*HD;
  const bh8 aq0 = *(const bh8*)(Qb + qrow + quad*8);
  const bh8 aq1 = *(const bh8*)(Qb + qrow + 32 + quad*8);

  f32x4 o[4];
#pragma unroll
  for (int i = 0; i < 4; ++i) o[i] = (f32x4){0.f,0.f,0.f,0.f};
  float m_r[4] = {-1e30f,-1e30f,-1e30f,-1e30f};
  float l_r[4] = {0.f,0.f,0.f,0.f};
  const float scale = 0.125f;
  const size_t kg = ((size_t)(b*SLEN))*EMBED + h*HD;   // K base
  const size_t vg = ((size_t)(bh*HD))*SLEN;            // VT base
  const int r0 = tid >> 3, ch = tid & 7;               // staging: rows r0,r0+32; 16B chunk ch

  for (int kt = 0; kt <= qt; ++kt) {
    const int k0 = kt*64;
    __syncthreads();                                   // prev-iter readers done
    *(bh8*)(Klds + r0*72 + ch*8)      = *(const bh8*)(Kb + kg + (size_t)(k0 + r0)*EMBED + ch*8);
    *(bh8*)(Klds + (r0+32)*72 + ch*8) = *(const bh8*)(Kb + kg + (size_t)(k0 + r0 + 32)*EMBED + ch*8);
    *(bh8*)(Vlds + r0*72 + ch*8)      = *(const bh8*)(VT + vg + (size_t)r0*SLEN + k0 + ch*8);
    *(bh8*)(Vlds + (r0+32)*72 + ch*8) = *(const bh8*)(VT + vg + (size_t)(r0+32)*SLEN + k0 + ch*8);
    __syncthreads();

    // S = Q K^T : 4 n-tiles of 16 keys
    f32x4 s[4];
#pragma unroll
    for (int nt = 0; nt < 4; ++nt) {
      s[nt] = (f32x4){0.f,0.f,0.f,0.f};
      const short* kp = Klds + (nt*16 + l16)*72 + quad*8;
      s[nt] = MFMA16(aq0, *(const bh8*)kp,        s[nt]);
      s[nt] = MFMA16(aq1, *(const bh8*)(kp + 32), s[nt]);
    }

    const bool lastTile = (kt == qt);
#pragma unroll
    for (int r = 0; r < 4; ++r) {
      const int q = qbase + quad*4 + r;
      float v[4];
#pragma unroll
      for (int nt = 0; nt < 4; ++nt) {
        v[nt] = s[nt][r]*scale;
        if (lastTile && (k0 + nt*16 + l16 > q)) v[nt] = -1e30f;
      }
      float mx = fmaxf(fmaxf(v[0], v[1]), fmaxf(v[2], v[3]));
#pragma unroll
      for (int off = 8; off >= 1; off >>= 1) mx = fmaxf(mx, __shfl_xor(mx, off));
      const float mnew = fmaxf(m_r[r], mx);
      const float alpha = __expf(m_r[r] - mnew);
      float p[4], rs = 0.f;
#pragma unroll
      for (int nt = 0; nt < 4; ++nt) { p[nt] = __expf(v[nt] - mnew); rs += p[nt]; }
#pragma unroll
      for (int off = 8; off >= 1; off >>= 1) rs += __shfl_xor(rs, off);
      l_r[r] = l_r[r]*alpha + rs;
      m_r[r] = mnew;
#pragma unroll
      for (int dt = 0; dt < 4; ++dt) o[dt][r] *= alpha;
      short* prow = Plds + w*1152 + (quad*4 + r)*72;
#pragma unroll
      for (int nt = 0; nt < 4; ++nt) prow[nt*16 + l16] = f2b(p[nt]);
    }

    // PV: P is wave-private (no barrier needed; in-wave LDS ordering)
    const short* pr = Plds + w*1152 + l16*72;
    const bh8 pf0 = *(const bh8*)(pr + quad*8);
    const bh8 pf1 = *(const bh8*)(pr + 32 + quad*8);
#pragma unroll
    for (int dt = 0; dt < 4; ++dt) {
      const short* vp = Vlds + (dt*16 + l16)*72 + quad*8;
      o[dt] = MFMA16(pf0, *(const bh8*)vp,        o[dt]);
      o[dt] = MFMA16(pf1, *(const bh8*)(vp + 32), o[dt]);
    }
  }

#pragma unroll
  for (int r = 0; r < 4; ++r) {
    const float inv = 1.0f / l_r[r];
    const size_t orow = ((size_t)(b*SLEN + qbase + quad*4 + r))*EMBED + h*HD;
#pragma unroll
    for (int dt = 0; dt < 4; ++dt)
      AOb[orow + dt*16 + l16] = f2b(o[dt][r]*inv);
  }
}

// ---------------- launcher ----------------
extern "C" void kernel_launch(void* const* d_in, const int* in_sizes, int n_in,
                              void* d_out, int out_size, void* d_ws, size_t ws_size,
                              hipStream_t stream) {
  const float* x    = (const float*)d_in[0];
  const float* cosb = (const float*)d_in[1];
  const float* sinb = (const float*)d_in[2];
  const float* Wq = (const float*)d_in[3];  const float* bq  = (const float*)d_in[4];
  const float* Wk = (const float*)d_in[5];  const float* bk  = (const float*)d_in[6];
  const float* Wv = (const float*)d_in[7];  const float* bv  = (const float*)d_in[8];
  const float* Wo = (const float*)d_in[9];  const float* bo  = (const float*)d_in[10];
  const float* W1 = (const float*)d_in[11]; const float* b1  = (const float*)d_in[12];
  const float* W2 = (const float*)d_in[13]; const float* b2  = (const float*)d_in[14];
  const float* g1 = (const float*)d_in[15]; const float* be1 = (const float*)d_in[16];
  const float* g2 = (const float*)d_in[17]; const float* be2 = (const float*)d_in[18];
  float* out = (float*)d_out;

  // workspace, peak 64MB
  char* ws = (char*)d_ws;
  const size_t MB = 1ull << 20;
  short* wqkvT = (short*)(ws + 0*MB);  // [0,6): Wq^T|Wk^T|Wv^T contiguous = [3072][1024]
  short* woT = (short*)(ws + 6*MB);    // [6,8)
  short* w2T = (short*)(ws + 0*MB);    // [0,8) reuse after O-proj
  short* w1T = (short*)(ws + 8*MB);    // [8,16)
  short* n1b = (short*)(ws + 16*MB);   // [16,24) -> X1b
  short* Qb  = (short*)(ws + 24*MB);   // [24,32) -> n2b
  short* Kb  = (short*)(ws + 32*MB);   // [32,40) -> Hb[0:8)
  short* Vb  = (short*)(ws + 40*MB);   // [40,48) -> Hb[8:16)
  short* AOb = (short*)(ws + 48*MB);   // [48,56) -> Hb[16:24)
  short* VTb = (short*)(ws + 56*MB);   // [56,64) -> Hb[24:32)
  short* X1b = (short*)(ws + 16*MB);
  short* n2b = (short*)(ws + 24*MB);
  short* Hb  = (short*)(ws + 32*MB);   // [32,64)

  // weight prep
  transpose_w<<<dim3(16,16), 256, 0, stream>>>(Wq, wqkvT,                1024, 1024);
  transpose_w<<<dim3(16,16), 256, 0, stream>>>(Wk, wqkvT + 1024*1024,    1024, 1024);
  transpose_w<<<dim3(16,16), 256, 0, stream>>>(Wv, wqkvT + 2*1024*1024,  1024, 1024);
  transpose_w<<<dim3(16,16), 256, 0, stream>>>(Wo, woT, 1024, 1024);
  transpose_w<<<dim3(64,16), 256, 0, stream>>>(W1, w1T, 1024, 4096);

  // LN1
  ln_kernel<<<MROWS, 256, 0, stream>>>(x, nullptr, g1, be1, n1b);

  // fused QKV projection (N=3072)
  gemm_bt<<<dim3(24,32), 256, 0, stream>>>(n1b, wqkvT, bq, bk, bv,
                                           nullptr, Qb, Kb, Vb, nullptr, nullptr,
                                           3072, 1024, 0, 1);

  // RoPE
  rope_kernel<<<8192, 256, 0, stream>>>(Qb, Kb, cosb, sinb);

  // V transpose for attention B-frags
  transpose_v<<<dim3(32,32), 256, 0, stream>>>(Vb, VTb);

  // flash attention
  attn_kernel<<<dim3(32,32), 256, 0, stream>>>(Qb, Kb, VTb, AOb);

  // O projection + residual(x) -> X1b
  gemm_bt<<<dim3(8,32), 256, 0, stream>>>(AOb, woT, bo, nullptr, nullptr,
                                          nullptr, X1b, nullptr, nullptr, x, nullptr,
                                          1024, 1024, 0, 0);

  // W2 transpose into freed region
  transpose_w<<<dim3(16,64), 256, 0, stream>>>(W2, w2T, 4096, 1024);

  // LN2
  ln_kernel<<<MROWS, 256, 0, stream>>>(nullptr, X1b, g2, be2, n2b);

  // FFN1 + GELU
  gemm_bt<<<dim3(32,32), 256, 0, stream>>>(n2b, w1T, b1, nullptr, nullptr,
                                           nullptr, Hb, nullptr, nullptr, nullptr, nullptr,
                                           4096, 1024, 1, 0);

  // FFN2 + residual(X1b) -> out (fp32)
  gemm_bt<<<dim3(8,32), 256, 0, stream>>>(Hb, w2T, b2, nullptr, nullptr,
                                          out, nullptr, nullptr, nullptr, nullptr, X1b,
                                          1024, 4096, 0, 0);
}